// Round 2
// baseline (3107.491 us; speedup 1.0000x reference)
//
#include <hip/hip_runtime.h>
#include <math.h>

#define BATCH 4
#define NSEQ 8193
#define NTOK 8192
#define CDIM 768
#define TOPK 12
#define NCHUNK 32      // 32 chunks x 256 tokens
#define BK 16
#define NDBLK 12       // 768 / 64

// ---------- sorted-descending top-k insertion (stable: strict >, scan in idx order) ----------
__device__ __forceinline__ void ins_f(float v, float (&lst)[TOPK]) {
  if (v > lst[TOPK - 1]) {
#pragma unroll
    for (int r = 0; r < TOPK; ++r) {
      bool g = v > lst[r];
      float disp = g ? lst[r] : v;
      lst[r] = g ? v : lst[r];
      v = disp;
    }
  }
}

__device__ __forceinline__ void ins_d(double v, int i, double (&lv)[TOPK], int (&li)[TOPK]) {
  if (v > lv[TOPK - 1]) {
#pragma unroll
    for (int r = 0; r < TOPK; ++r) {
      bool g = v > lv[r];
      double dv2 = g ? lv[r] : v;
      int di = g ? li[r] : i;
      lv[r] = g ? v : lv[r];
      li[r] = g ? i : li[r];
      v = dv2;
      i = di;
    }
  }
}

// ---------- kernel A: cls-token QKV rows (token 0), fp32 ----------
__global__ void cls_kernel(const float* __restrict__ x, const float* __restrict__ W,
                           const float* __restrict__ bias, float* __restrict__ cls) {
  int idx = blockIdx.x * 256 + threadIdx.x;  // [0, 3*B*C)
  if (idx >= 3 * BATCH * CDIM) return;
  int qty = idx / (BATCH * CDIM);
  int rem = idx % (BATCH * CDIM);
  int b = rem / CDIM;
  int d = rem % CDIM;
  int o = qty * CDIM + d;
  const float* xr = x + (size_t)b * NSEQ * CDIM;  // token 0 row
  const float* wr = W + (size_t)o * CDIM;
  float s0 = 0.f, s1 = 0.f, s2 = 0.f, s3 = 0.f;
  for (int c = 0; c < CDIM; c += 4) {
    s0 = fmaf(xr[c + 0], wr[c + 0], s0);
    s1 = fmaf(xr[c + 1], wr[c + 1], s1);
    s2 = fmaf(xr[c + 2], wr[c + 2], s2);
    s3 = fmaf(xr[c + 3], wr[c + 3], s3);
  }
  float s = (s0 + s1) + (s2 + s3);
  s += bias[o];
  cls[qty * (BATCH * CDIM) + b * CDIM + d] = s;  // cls[3][B][C]
}

// ---------- kernel B: fused QKV GEMM (q,k fp32; v fp64) + m-write + per-chunk top-12 ----------
__launch_bounds__(256, 2)
__global__ void fused_kernel(const float* __restrict__ x, const float* __restrict__ W,
                             const float* __restrict__ bias, const float* __restrict__ cls,
                             float* __restrict__ out,
                             float* __restrict__ candQ, float* __restrict__ candK,
                             double* __restrict__ candVv, int* __restrict__ candVi) {
  __shared__ __align__(16) union SM {
    struct { float xs[BK][132]; float w[3][BK][68]; } st;  // staging (transposed tiles)
    float bufq[128][68];                                   // epilogue fp32 redistribution
    double bufv[128][33];                                  // epilogue fp64 redistribution (32-d half)
  } sm;

  const int tid = threadIdx.x;
  const int chunk = blockIdx.x;  // 0..31
  const int dblk = blockIdx.y;   // 0..11
  const int b = blockIdx.z;      // 0..3
  const int tg = tid >> 4;       // token group 0..15 (8 tokens each)
  const int dg = tid & 15;       // d group 0..15 (4 d each)
  const int d0 = dblk * 64;

  // persistent top-k state across the 2 subtiles (owned by scan threads tid<64, d = d0+tid)
  float tq[TOPK], tk[TOPK];
  double tvv[TOPK];
  int tvi[TOPK];
#pragma unroll
  for (int r = 0; r < TOPK; ++r) { tq[r] = -INFINITY; tk[r] = -INFINITY; tvv[r] = -INFINITY; tvi[r] = 0; }

  // per-thread cls/bias values for its 4 d's
  float qc[4], kc[4], iv[4], bq[4], bk[4], bvs[4];
#pragma unroll
  for (int j = 0; j < 4; ++j) {
    int d = d0 + dg * 4 + j;
    float q_ = cls[0 * (BATCH * CDIM) + b * CDIM + d];
    float k_ = cls[1 * (BATCH * CDIM) + b * CDIM + d];
    float v_ = cls[2 * (BATCH * CDIM) + b * CDIM + d];
    qc[j] = q_; kc[j] = k_;
    iv[j] = (q_ * k_) * (1.0f + fabsf(v_));
    bq[j] = bias[d]; bk[j] = bias[CDIM + d]; bvs[j] = bias[2 * CDIM + d];
  }

  for (int sub = 0; sub < 2; ++sub) {
    const int n0 = 1 + chunk * 256 + sub * 128;  // global token row (skip cls row 0)
    float accq[8][4], acck[8][4];
    double accv[8][4];
#pragma unroll
    for (int i2 = 0; i2 < 8; ++i2)
#pragma unroll
      for (int j = 0; j < 4; ++j) { accq[i2][j] = 0.f; acck[i2][j] = 0.f; accv[i2][j] = 0.0; }

    for (int k0 = 0; k0 < CDIM; k0 += BK) {
      __syncthreads();
      // stage x tile (128 tokens x 16 k), transposed to xs[k][token]
#pragma unroll
      for (int r = 0; r < 2; ++r) {
        int id = tid + r * 256;
        int tok = id >> 2, kq = id & 3;
        const float4 v4 = *(const float4*)(x + ((size_t)(b * NSEQ + n0 + tok)) * CDIM + k0 + kq * 4);
        sm.st.xs[kq * 4 + 0][tok] = v4.x;
        sm.st.xs[kq * 4 + 1][tok] = v4.y;
        sm.st.xs[kq * 4 + 2][tok] = v4.z;
        sm.st.xs[kq * 4 + 3][tok] = v4.w;
      }
      // stage W tiles (3 x 64 d x 16 k), transposed to w[qty][k][d]
#pragma unroll
      for (int r = 0; r < 3; ++r) {
        int id = tid + r * 256;
        int qty = id >> 8, rem = id & 255;
        int dloc = rem >> 2, kq = rem & 3;
        const float4 v4 = *(const float4*)(W + (size_t)(qty * CDIM + d0 + dloc) * CDIM + k0 + kq * 4);
        sm.st.w[qty][kq * 4 + 0][dloc] = v4.x;
        sm.st.w[qty][kq * 4 + 1][dloc] = v4.y;
        sm.st.w[qty][kq * 4 + 2][dloc] = v4.z;
        sm.st.w[qty][kq * 4 + 3][dloc] = v4.w;
      }
      __syncthreads();
#pragma unroll
      for (int kk = 0; kk < BK; ++kk) {
        float a[8];
        const float4 a0 = *(const float4*)&sm.st.xs[kk][tg * 8];
        const float4 a1 = *(const float4*)&sm.st.xs[kk][tg * 8 + 4];
        a[0] = a0.x; a[1] = a0.y; a[2] = a0.z; a[3] = a0.w;
        a[4] = a1.x; a[5] = a1.y; a[6] = a1.z; a[7] = a1.w;
        const float4 wq4 = *(const float4*)&sm.st.w[0][kk][dg * 4];
        const float4 wk4 = *(const float4*)&sm.st.w[1][kk][dg * 4];
        const float4 wv4 = *(const float4*)&sm.st.w[2][kk][dg * 4];
        const float wqa[4] = {wq4.x, wq4.y, wq4.z, wq4.w};
        const float wka[4] = {wk4.x, wk4.y, wk4.z, wk4.w};
        const double wva[4] = {(double)wv4.x, (double)wv4.y, (double)wv4.z, (double)wv4.w};
#pragma unroll
        for (int i2 = 0; i2 < 8; ++i2) {
          const float av = a[i2];
          const double ad = (double)av;
#pragma unroll
          for (int j = 0; j < 4; ++j) {
            accq[i2][j] = fmaf(av, wqa[j], accq[i2][j]);
            acck[i2][j] = fmaf(av, wka[j], acck[i2][j]);
            accv[i2][j] = fma(ad, wva[j], accv[i2][j]);
          }
        }
      }
    }

    // bias
#pragma unroll
    for (int i2 = 0; i2 < 8; ++i2)
#pragma unroll
      for (int j = 0; j < 4; ++j) {
        accq[i2][j] += bq[j];
        acck[i2][j] += bk[j];
        accv[i2][j] += (double)bvs[j];
      }

    // write m = v^2 + 2v + inter_v into d_out rows 1..8192 (recomputed per pass from accv)
#pragma unroll
    for (int i2 = 0; i2 < 8; ++i2) {
      float4 mf;
      mf.x = (float)fma(accv[i2][0], accv[i2][0] + 2.0, (double)iv[0]);
      mf.y = (float)fma(accv[i2][1], accv[i2][1] + 2.0, (double)iv[1]);
      mf.z = (float)fma(accv[i2][2], accv[i2][2] + 2.0, (double)iv[2]);
      mf.w = (float)fma(accv[i2][3], accv[i2][3] + 2.0, (double)iv[3]);
      *(float4*)(out + ((size_t)(b * NSEQ + n0 + tg * 8 + i2)) * CDIM + d0 + dg * 4) = mf;
    }

    // ---- pass Q: a_q = q_cls*k + q
    __syncthreads();
#pragma unroll
    for (int i2 = 0; i2 < 8; ++i2) {
      float4 t4;
      t4.x = fmaf(qc[0], acck[i2][0], accq[i2][0]);
      t4.y = fmaf(qc[1], acck[i2][1], accq[i2][1]);
      t4.z = fmaf(qc[2], acck[i2][2], accq[i2][2]);
      t4.w = fmaf(qc[3], acck[i2][3], accq[i2][3]);
      *(float4*)&sm.bufq[tg * 8 + i2][dg * 4] = t4;
    }
    __syncthreads();
    if (tid < 64) {
      for (int t = 0; t < 128; ++t) ins_f(sm.bufq[t][tid], tq);
    }

    // ---- pass K: a_k = k_cls*q + k
    __syncthreads();
#pragma unroll
    for (int i2 = 0; i2 < 8; ++i2) {
      float4 t4;
      t4.x = fmaf(kc[0], accq[i2][0], acck[i2][0]);
      t4.y = fmaf(kc[1], accq[i2][1], acck[i2][1]);
      t4.z = fmaf(kc[2], accq[i2][2], acck[i2][2]);
      t4.w = fmaf(kc[3], accq[i2][3], acck[i2][3]);
      *(float4*)&sm.bufq[tg * 8 + i2][dg * 4] = t4;
    }
    __syncthreads();
    if (tid < 64) {
      for (int t = 0; t < 128; ++t) ins_f(sm.bufq[t][tid], tk);
    }

    // ---- pass V (fp64, two 32-d halves): m ordering must be exact
    for (int half = 0; half < 2; ++half) {
      __syncthreads();
      if ((dg >> 3) == half) {
        int dc = (dg & 7) * 4;
#pragma unroll
        for (int i2 = 0; i2 < 8; ++i2) {
#pragma unroll
          for (int j = 0; j < 4; ++j)
            sm.bufv[tg * 8 + i2][dc + j] = fma(accv[i2][j], accv[i2][j] + 2.0, (double)iv[j]);
        }
      }
      __syncthreads();
      if (tid < 64 && (tid >> 5) == half) {
        int dc = tid & 31;
        int gbase = chunk * 256 + sub * 128;
        for (int t = 0; t < 128; ++t) ins_d(sm.bufv[t][dc], gbase + t, tvv, tvi);
      }
    }
  }  // sub

  // write per-chunk candidates
  if (tid < 64) {
    int d = d0 + tid;
    size_t base = ((size_t)(b * CDIM + d) * NCHUNK + chunk) * TOPK;
#pragma unroll
    for (int r = 0; r < TOPK; ++r) {
      candQ[base + r] = tq[r];
      candK[base + r] = tk[r];
      candVv[base + r] = tvv[r];
      candVi[base + r] = tvi[r];
    }
  }
}

// ---------- kernel C: merge candidates -> qm/km/vm/vidx ----------
__global__ void merge_kernel(const float* __restrict__ cls,
                             const float* __restrict__ candQ, const float* __restrict__ candK,
                             const double* __restrict__ candVv, const int* __restrict__ candVi,
                             float* __restrict__ qm, float* __restrict__ km,
                             float* __restrict__ vm, int* __restrict__ vidx) {
  int idx = blockIdx.x * 256 + threadIdx.x;  // [0, B*C)
  int b = idx / CDIM, d = idx % CDIM;
  float tq[TOPK], tk[TOPK];
  double tv[TOPK];
  int ti[TOPK];
#pragma unroll
  for (int r = 0; r < TOPK; ++r) { tq[r] = -INFINITY; tk[r] = -INFINITY; tv[r] = -INFINITY; ti[r] = 0; }
  size_t base = (size_t)(b * CDIM + d) * NCHUNK * TOPK;
  for (int c = 0; c < NCHUNK * TOPK; ++c) {
    ins_f(candQ[base + c], tq);
    ins_f(candK[base + c], tk);
    ins_d(candVv[base + c], candVi[base + c], tv, ti);
  }
  qm[(b * 13 + 0) * CDIM + d] = cls[0 * (BATCH * CDIM) + b * CDIM + d];
  km[(b * 13 + 0) * CDIM + d] = cls[1 * (BATCH * CDIM) + b * CDIM + d];
  vm[(b * 13 + 0) * CDIM + d] = cls[2 * (BATCH * CDIM) + b * CDIM + d];
#pragma unroll
  for (int r = 0; r < TOPK; ++r) {
    qm[(b * 13 + 1 + r) * CDIM + d] = tq[r];
    km[(b * 13 + 1 + r) * CDIM + d] = tk[r];
    vm[(b * 13 + 1 + r) * CDIM + d] = (float)tv[r];
    vidx[(b * TOPK + r) * CDIM + d] = ti[r];
  }
}

// ---------- kernel D: 13x13 attention + scatter-add ----------
__global__ void attn_kernel(const float* __restrict__ qm, const float* __restrict__ km,
                            const float* __restrict__ vm, const int* __restrict__ vidx,
                            float* __restrict__ out) {
  const int b = blockIdx.x, tid = threadIdx.x;
  __shared__ float att[13][16];
  if (tid < 169) {
    int i = tid / 13, j = tid % 13;
    const float* qr = qm + (size_t)(b * 13 + i) * CDIM;
    const float* kr = km + (size_t)(b * 13 + j) * CDIM;
    float s0 = 0.f, s1 = 0.f, s2 = 0.f, s3 = 0.f;
    for (int c = 0; c < CDIM; c += 4) {
      s0 = fmaf(qr[c + 0], kr[c + 0], s0);
      s1 = fmaf(qr[c + 1], kr[c + 1], s1);
      s2 = fmaf(qr[c + 2], kr[c + 2], s2);
      s3 = fmaf(qr[c + 3], kr[c + 3], s3);
    }
    att[i][j] = ((s0 + s1) + (s2 + s3)) * 0.03608439182435161f;  // 768^-0.5
  }
  __syncthreads();
  if (tid < 13) {
    float mx = -INFINITY;
    float e[13];
#pragma unroll
    for (int j = 0; j < 13; ++j) mx = fmaxf(mx, att[tid][j]);
    float sum = 0.f;
#pragma unroll
    for (int j = 0; j < 13; ++j) { e[j] = expf(att[tid][j] - mx); sum += e[j]; }
    float inv = 1.f / sum;
#pragma unroll
    for (int j = 0; j < 13; ++j) att[tid][j] = e[j] * inv;
  }
  __syncthreads();
  for (int i = tid; i < 13 * CDIM; i += 256) {
    int j = i / CDIM, d = i % CDIM;
    float s = 0.f;
#pragma unroll
    for (int kk = 0; kk < 13; ++kk) s = fmaf(att[j][kk], vm[(size_t)(b * 13 + kk) * CDIM + d], s);
    if (j == 0) {
      out[(size_t)b * NSEQ * CDIM + d] = s;  // cls output row
    } else {
      int t = vidx[(b * TOPK + (j - 1)) * CDIM + d];
      size_t o = ((size_t)b * NSEQ + 1 + t) * CDIM + d;
      out[o] += s;  // unique (row,d) targets: no collisions
    }
  }
}

extern "C" void kernel_launch(void* const* d_in, const int* in_sizes, int n_in,
                              void* d_out, int out_size, void* d_ws, size_t ws_size,
                              hipStream_t stream) {
  const float* x = (const float*)d_in[0];
  const float* W = (const float*)d_in[1];
  const float* bias = (const float*)d_in[2];
  float* out = (float*)d_out;
  char* ws = (char*)d_ws;

  float* cls = (float*)(ws + 0);               // 36864 B
  float* qm = (float*)(ws + 36864);            // 159744 B
  float* km = (float*)(ws + 196608);           // 159744 B
  float* vm = (float*)(ws + 356352);           // 159744 B
  int* vidx = (int*)(ws + 516096);             // 147456 B
  double* candVv = (double*)(ws + 663552);     // 9437184 B (8-aligned)
  float* candQ = (float*)(ws + 10100736);      // 4718592 B
  float* candK = (float*)(ws + 14819328);      // 4718592 B
  int* candVi = (int*)(ws + 19537920);         // 4718592 B -> total 24256512 B

  hipLaunchKernelGGL(cls_kernel, dim3(36), dim3(256), 0, stream, x, W, bias, cls);
  hipLaunchKernelGGL(fused_kernel, dim3(NCHUNK, NDBLK, BATCH), dim3(256), 0, stream,
                     x, W, bias, cls, out, candQ, candK, candVv, candVi);
  hipLaunchKernelGGL(merge_kernel, dim3(12), dim3(256), 0, stream,
                     cls, candQ, candK, candVv, candVi, qm, km, vm, vidx);
  hipLaunchKernelGGL(attn_kernel, dim3(BATCH), dim3(256), 0, stream, qm, km, vm, vidx, out);
}